// Round 10
// baseline (3831.419 us; speedup 1.0000x reference)
//
#include <hip/hip_runtime.h>
#include <hip/hip_bf16.h>
#include <math.h>

typedef __bf16 bf16_t;
typedef __bf16 bf16x4 __attribute__((ext_vector_type(4)));
typedef __bf16 bf16x8 __attribute__((ext_vector_type(8)));
typedef float  f32x4  __attribute__((ext_vector_type(4)));

#define DIN   3072
#define NOUT  24576
#define HALF  12288
#define MTOK  4096
#define BM    128
#define BN    128
#define BK    64

// fused-prepass block ranges (small kernels first: overlap under quant_w's body)
#define NB_LORA  (MTOK / 8)                       // 512
#define NB_QX    (MTOK)                           // 4096
#define NB_CVT   (NOUT * 32 / 4 / 256)            // 768
#define NB_QW    (NOUT * (DIN / 4) / 256)         // 73728
#define B0       (NB_LORA)
#define B1       (B0 + NB_QX)
#define B2       (B1 + NB_CVT)
#define NB_PREP  (B2 + NB_QW)

#define GLD16(gp, lp) \
    __builtin_amdgcn_global_load_lds((const __attribute__((address_space(1))) void*)(gp), \
                                     (__attribute__((address_space(3))) void*)(lp), 16, 0, 0)

// ---------------- fused prepass: lora_t | quant_x | cvt_lu | quant_w --------------
__global__ __launch_bounds__(256) void k_prep(const float* __restrict__ x,
                                              const float* __restrict__ w,
                                              const float* __restrict__ ld,
                                              const float* __restrict__ lu,
                                              bf16_t* __restrict__ xq,
                                              bf16_t* __restrict__ wq,
                                              bf16_t* __restrict__ T,
                                              bf16_t* __restrict__ lub) {
    const int bid = blockIdx.x;
    const int t = threadIdx.x;

    if (bid < B0) {
        // ---- T = x @ lora_down^T (full-precision x), 8 tokens x 32 ranks ----
        int r = t & 31;
        int m = bid * 8 + (t >> 5);
        const float4* xr = reinterpret_cast<const float4*>(x + (size_t)m * DIN);
        const float4* lr = reinterpret_cast<const float4*>(ld + (size_t)r * DIN);
        float acc = 0.f;
#pragma unroll 4
        for (int i = 0; i < DIN / 4; ++i) {
            float4 a = xr[i], b = lr[i];
            acc += a.x * b.x + a.y * b.y + a.z * b.z + a.w * b.w;
        }
        T[(size_t)m * 32 + r] = (bf16_t)acc;
    } else if (bid < B1) {
        // ---- per-token activation int4 fake-quant -> bf16 ----
        int m = bid - B0;
        const float4* row = reinterpret_cast<const float4*>(x + (size_t)m * DIN);
        float4 v[3];
        float vm = 0.f;
#pragma unroll
        for (int i = 0; i < 3; ++i) {
            v[i] = row[t + i * 256];
            vm = fmaxf(vm, fmaxf(fmaxf(fabsf(v[i].x), fabsf(v[i].y)),
                                 fmaxf(fabsf(v[i].z), fabsf(v[i].w))));
        }
#pragma unroll
        for (int d = 1; d < 64; d <<= 1) vm = fmaxf(vm, __shfl_xor(vm, d));
        __shared__ float sm[4];
        if ((t & 63) == 0) sm[t >> 6] = vm;
        __syncthreads();
        vm = fmaxf(fmaxf(sm[0], sm[1]), fmaxf(sm[2], sm[3]));
        float s = fmaxf(vm * (1.f / 7.f), 1e-8f);
        float inv = 1.f / s;
        bf16x4* orow = reinterpret_cast<bf16x4*>(xq + (size_t)m * DIN);
#pragma unroll
        for (int i = 0; i < 3; ++i) {
            bf16x4 o;
            o[0] = (bf16_t)(fminf(fmaxf(rintf(v[i].x * inv), -8.f), 7.f) * s);
            o[1] = (bf16_t)(fminf(fmaxf(rintf(v[i].y * inv), -8.f), 7.f) * s);
            o[2] = (bf16_t)(fminf(fmaxf(rintf(v[i].z * inv), -8.f), 7.f) * s);
            o[3] = (bf16_t)(fminf(fmaxf(rintf(v[i].w * inv), -8.f), 7.f) * s);
            orow[t + i * 256] = o;
        }
    } else if (bid < B2) {
        // ---- cast lora_up f32 -> bf16 ----
        size_t idx = (size_t)(bid - B1) * 256 + t;
        float4 v = reinterpret_cast<const float4*>(lu)[idx];
        bf16x4 o;
        o[0] = (bf16_t)v.x; o[1] = (bf16_t)v.y; o[2] = (bf16_t)v.z; o[3] = (bf16_t)v.w;
        reinterpret_cast<bf16x4*>(lub)[idx] = o;
    } else {
        // ---- per-(row, group-of-64) weight int4 fake-quant -> bf16 ----
        size_t idx = (size_t)(bid - B2) * 256 + t;   // float4 index
        float4 v = reinterpret_cast<const float4*>(w)[idx];
        float vm = fmaxf(fmaxf(fabsf(v.x), fabsf(v.y)), fmaxf(fabsf(v.z), fabsf(v.w)));
        vm = fmaxf(vm, __shfl_xor(vm, 1));
        vm = fmaxf(vm, __shfl_xor(vm, 2));
        vm = fmaxf(vm, __shfl_xor(vm, 4));
        vm = fmaxf(vm, __shfl_xor(vm, 8));
        float s = fmaxf(vm * (1.f / 7.f), 1e-8f);
        float inv = 1.f / s;
        bf16x4 o;
        o[0] = (bf16_t)(fminf(fmaxf(rintf(v.x * inv), -8.f), 7.f) * s);
        o[1] = (bf16_t)(fminf(fmaxf(rintf(v.y * inv), -8.f), 7.f) * s);
        o[2] = (bf16_t)(fminf(fmaxf(rintf(v.z * inv), -8.f), 7.f) * s);
        o[3] = (bf16_t)(fminf(fmaxf(rintf(v.w * inv), -8.f), 7.f) * s);
        reinterpret_cast<bf16x4*>(wq)[idx] = o;
    }
}

// ---------------- K4: fused GEMM (h + gate tiles) + LoRA + GEGLU ------------------
// r3 structure, LDS shrunk to 48 KB (bf16 epilogue exchange aliased onto staging)
// -> 3 blocks/CU (144 KB LDS, launch_bounds(512,6)). More cross-block overlap
// fills the per-block barrier/vmcnt drain windows (m114 mechanism).
__global__ __launch_bounds__(512, 6) void k_gemm(const bf16_t* __restrict__ xq,
                                                 const bf16_t* __restrict__ wq,
                                                 const bf16_t* __restrict__ T,
                                                 const bf16_t* __restrict__ lub,
                                                 float* __restrict__ out) {
    __shared__ __align__(16) char smem[49152];       // staging 48KB; exch 128x132 bf16
    bf16_t* sA = (bf16_t*)smem;                      // [128][64]
    bf16_t* sH = sA + BM * BK;
    bf16_t* sG = sH + BN * BK;

    int tid = threadIdx.x, lane = tid & 63, w = tid >> 6;
    int half = w >> 2;                 // 0 = H, 1 = G
    int wr = (w & 3) >> 1, wc = w & 1;

    // XCD-bijective swizzle (3072 % 8 == 0)
    int nwg = gridDim.x;
    int cpx = nwg >> 3;
    int swz = (blockIdx.x & 7) * cpx + (blockIdx.x >> 3);
    int mt = swz & 31, nt = swz >> 5;  // mt fast: neighbors share B tiles
    int m0 = mt * BM, c0 = nt * BN;

    f32x4 acc[4][4];
#pragma unroll
    for (int i = 0; i < 4; ++i)
#pragma unroll
        for (int j = 0; j < 4; ++j) acc[i][j] = (f32x4){0.f, 0.f, 0.f, 0.f};

    const char* sBb = (const char*)(half ? sG : sH);
    const char* sAb = (const char*)sA;

    for (int k0 = 0; k0 < DIN; k0 += BK) {
        __syncthreads();
        // stage 3 tiles of 128x64 bf16; 1024 16B-chunks each; 512 lanes -> 2 rounds.
#pragma unroll
        for (int r = 0; r < 2; ++r) {
            int chunk = r * 512 + tid;
            int row = chunk >> 3;
            int gc = ((chunk & 7) ^ (row & 7)) * 8;
            int ldsoff = r * 4096 + w * 512;
            GLD16(xq + (size_t)(m0 + row) * DIN + k0 + gc, sA + ldsoff);
            GLD16(wq + (size_t)(c0 + row) * DIN + k0 + gc, sH + ldsoff);
            GLD16(wq + (size_t)(c0 + HALF + row) * DIN + k0 + gc, sG + ldsoff);
        }
        __syncthreads();   // vmcnt(0) drain before barrier

#pragma unroll
        for (int ks = 0; ks < 2; ++ks) {
            int c16 = ks * 4 + (lane >> 4);
            bf16x8 a[4], b[4];
#pragma unroll
            for (int i = 0; i < 4; ++i) {
                int ra = wr * 64 + i * 16 + (lane & 15);
                int rb = wc * 64 + i * 16 + (lane & 15);
                a[i] = *reinterpret_cast<const bf16x8*>(sAb + ra * 128 + ((c16 ^ (ra & 7)) << 4));
                b[i] = *reinterpret_cast<const bf16x8*>(sBb + rb * 128 + ((c16 ^ (rb & 7)) << 4));
            }
#pragma unroll
            for (int m = 0; m < 4; ++m)
#pragma unroll
                for (int n = 0; n < 4; ++n)
                    acc[m][n] = __builtin_amdgcn_mfma_f32_16x16x32_bf16(a[m], b[n], acc[m][n], 0, 0, 0);
        }
    }

    // ---- LoRA correction: one K=32 MFMA per fragment (RANK == 32) ----
    {
        bf16x8 tf[4];
#pragma unroll
        for (int m = 0; m < 4; ++m)
            tf[m] = *reinterpret_cast<const bf16x8*>(
                T + (size_t)(m0 + wr * 64 + m * 16 + (lane & 15)) * 32 + (lane >> 4) * 8);
#pragma unroll
        for (int n = 0; n < 4; ++n) {
            bf16x8 lu = *reinterpret_cast<const bf16x8*>(
                lub + (size_t)(c0 + half * HALF + wc * 64 + n * 16 + (lane & 15)) * 32 + (lane >> 4) * 8);
#pragma unroll
            for (int m = 0; m < 4; ++m)
                acc[m][n] = __builtin_amdgcn_mfma_f32_16x16x32_bf16(tf[m], lu, acc[m][n], 0, 0, 0);
        }
    }

    // ---- GEGLU epilogue via bf16 LDS exchange [128][132] (pad kills conflicts) ----
    __syncthreads();                    // all LDS staging reads done; reuse smem
    bf16_t* exch = (bf16_t*)smem;
    if (half) {
#pragma unroll
        for (int m = 0; m < 4; ++m)
#pragma unroll
            for (int n = 0; n < 4; ++n) {
                int col = wc * 64 + n * 16 + (lane & 15);
#pragma unroll
                for (int r = 0; r < 4; ++r) {
                    int row = wr * 64 + m * 16 + (lane >> 4) * 4 + r;
                    float g = acc[m][n][r];
                    float gl = 0.5f * g * (1.0f + erff(g * 0.70710678118654752f));
                    exch[row * 132 + col] = (bf16_t)gl;
                }
            }
    }
    __syncthreads();
    if (!half) {
#pragma unroll
        for (int m = 0; m < 4; ++m)
#pragma unroll
            for (int n = 0; n < 4; ++n) {
                int col = wc * 64 + n * 16 + (lane & 15);
#pragma unroll
                for (int r = 0; r < 4; ++r) {
                    int row = wr * 64 + m * 16 + (lane >> 4) * 4 + r;
                    float gl = (float)exch[row * 132 + col];
                    out[(size_t)(m0 + row) * HALF + c0 + col] = acc[m][n][r] * gl;
                }
            }
    }
}

extern "C" void kernel_launch(void* const* d_in, const int* in_sizes, int n_in,
                              void* d_out, int out_size, void* d_ws, size_t ws_size,
                              hipStream_t stream) {
    const float* x  = (const float*)d_in[0];   // [1,4096,3072]
    const float* wr = (const float*)d_in[1];   // [24576,3072]
    const float* ld = (const float*)d_in[2];   // [32,3072]
    const float* lu = (const float*)d_in[3];   // [24576,32]
    float* out = (float*)d_out;                // [4096,12288] f32

    bf16_t* xq  = (bf16_t*)d_ws;
    bf16_t* wq  = xq + (size_t)MTOK * DIN;
    bf16_t* T   = wq + (size_t)NOUT * DIN;
    bf16_t* lub = T  + (size_t)MTOK * 32;

    k_prep<<<NB_PREP, 256, 0, stream>>>(x, wr, ld, lu, xq, wq, T, lub);
    k_gemm<<<(MTOK / BM) * (HALF / BN), 512, 0, stream>>>(xq, wq, T, lub, out);
}

// Round 11
// 955.115 us; speedup vs baseline: 4.0115x; 4.0115x over previous
//
#include <hip/hip_runtime.h>
#include <hip/hip_bf16.h>
#include <math.h>

typedef __bf16 bf16_t;
typedef __bf16 bf16x4 __attribute__((ext_vector_type(4)));
typedef __bf16 bf16x8 __attribute__((ext_vector_type(8)));
typedef float  f32x4  __attribute__((ext_vector_type(4)));

#define DIN   3072
#define NOUT  24576
#define HALF  12288
#define MTOK  4096
#define BM    128
#define BN    128
#define BK    64
#define NT    48          // DIN / BK

// fused-prepass block ranges (small kernels first: overlap under quant_w's body)
#define NB_LORA  (MTOK / 8)                       // 512
#define NB_QX    (MTOK)                           // 4096
#define NB_CVT   (NOUT * 32 / 4 / 256)            // 768
#define NB_QW    (NOUT * (DIN / 4) / 256)         // 73728
#define B0       (NB_LORA)
#define B1       (B0 + NB_QX)
#define B2       (B1 + NB_CVT)
#define NB_PREP  (B2 + NB_QW)

#define GLD16(gp, lp) \
    __builtin_amdgcn_global_load_lds((const __attribute__((address_space(1))) void*)(gp), \
                                     (__attribute__((address_space(3))) void*)(lp), 16, 0, 0)

#define BAR()    __builtin_amdgcn_s_barrier()
#define WAITV(N) asm volatile("s_waitcnt vmcnt(" #N ")" ::: "memory")
#define SCHED0() __builtin_amdgcn_sched_barrier(0)

// ---------------- fused prepass: lora_t | quant_x | cvt_lu | quant_w --------------
__global__ __launch_bounds__(256) void k_prep(const float* __restrict__ x,
                                              const float* __restrict__ w,
                                              const float* __restrict__ ld,
                                              const float* __restrict__ lu,
                                              bf16_t* __restrict__ xq,
                                              bf16_t* __restrict__ wq,
                                              bf16_t* __restrict__ T,
                                              bf16_t* __restrict__ lub) {
    const int bid = blockIdx.x;
    const int t = threadIdx.x;

    if (bid < B0) {
        // ---- T = x @ lora_down^T (full-precision x), 8 tokens x 32 ranks ----
        int r = t & 31;
        int m = bid * 8 + (t >> 5);
        const float4* xr = reinterpret_cast<const float4*>(x + (size_t)m * DIN);
        const float4* lr = reinterpret_cast<const float4*>(ld + (size_t)r * DIN);
        float acc = 0.f;
#pragma unroll 4
        for (int i = 0; i < DIN / 4; ++i) {
            float4 a = xr[i], b = lr[i];
            acc += a.x * b.x + a.y * b.y + a.z * b.z + a.w * b.w;
        }
        T[(size_t)m * 32 + r] = (bf16_t)acc;
    } else if (bid < B1) {
        // ---- per-token activation int4 fake-quant -> bf16 ----
        int m = bid - B0;
        const float4* row = reinterpret_cast<const float4*>(x + (size_t)m * DIN);
        float4 v[3];
        float vm = 0.f;
#pragma unroll
        for (int i = 0; i < 3; ++i) {
            v[i] = row[t + i * 256];
            vm = fmaxf(vm, fmaxf(fmaxf(fabsf(v[i].x), fabsf(v[i].y)),
                                 fmaxf(fabsf(v[i].z), fabsf(v[i].w))));
        }
#pragma unroll
        for (int d = 1; d < 64; d <<= 1) vm = fmaxf(vm, __shfl_xor(vm, d));
        __shared__ float sm[4];
        if ((t & 63) == 0) sm[t >> 6] = vm;
        __syncthreads();
        vm = fmaxf(fmaxf(sm[0], sm[1]), fmaxf(sm[2], sm[3]));
        float s = fmaxf(vm * (1.f / 7.f), 1e-8f);
        float inv = 1.f / s;
        bf16x4* orow = reinterpret_cast<bf16x4*>(xq + (size_t)m * DIN);
#pragma unroll
        for (int i = 0; i < 3; ++i) {
            bf16x4 o;
            o[0] = (bf16_t)(fminf(fmaxf(rintf(v[i].x * inv), -8.f), 7.f) * s);
            o[1] = (bf16_t)(fminf(fmaxf(rintf(v[i].y * inv), -8.f), 7.f) * s);
            o[2] = (bf16_t)(fminf(fmaxf(rintf(v[i].z * inv), -8.f), 7.f) * s);
            o[3] = (bf16_t)(fminf(fmaxf(rintf(v[i].w * inv), -8.f), 7.f) * s);
            orow[t + i * 256] = o;
        }
    } else if (bid < B2) {
        // ---- cast lora_up f32 -> bf16 ----
        size_t idx = (size_t)(bid - B1) * 256 + t;
        float4 v = reinterpret_cast<const float4*>(lu)[idx];
        bf16x4 o;
        o[0] = (bf16_t)v.x; o[1] = (bf16_t)v.y; o[2] = (bf16_t)v.z; o[3] = (bf16_t)v.w;
        reinterpret_cast<bf16x4*>(lub)[idx] = o;
    } else {
        // ---- per-(row, group-of-64) weight int4 fake-quant -> bf16 ----
        size_t idx = (size_t)(bid - B2) * 256 + t;   // float4 index
        float4 v = reinterpret_cast<const float4*>(w)[idx];
        float vm = fmaxf(fmaxf(fabsf(v.x), fabsf(v.y)), fmaxf(fabsf(v.z), fabsf(v.w)));
        vm = fmaxf(vm, __shfl_xor(vm, 1));
        vm = fmaxf(vm, __shfl_xor(vm, 2));
        vm = fmaxf(vm, __shfl_xor(vm, 4));
        vm = fmaxf(vm, __shfl_xor(vm, 8));
        float s = fmaxf(vm * (1.f / 7.f), 1e-8f);
        float inv = 1.f / s;
        bf16x4 o;
        o[0] = (bf16_t)(fminf(fmaxf(rintf(v.x * inv), -8.f), 7.f) * s);
        o[1] = (bf16_t)(fminf(fmaxf(rintf(v.y * inv), -8.f), 7.f) * s);
        o[2] = (bf16_t)(fminf(fmaxf(rintf(v.z * inv), -8.f), 7.f) * s);
        o[3] = (bf16_t)(fminf(fmaxf(rintf(v.w * inv), -8.f), 7.f) * s);
        reinterpret_cast<bf16x4*>(wq)[idx] = o;
    }
}

// ---------------- K4: r3 compute structure + 3-deep counted prefetch (T4) ---------
// 512 thr = 8 waves. Waves 0-3: H tile (2x2 of 64x64); waves 4-7: G tile.
// LDS: 3 circular buffers x 48 KB {A|BH|BG} = 144 KB, 1 block/CU.
// Per K-tile t: WAITV(12) (tile t landed; t+1,t+2 = 12 loads in flight, issued
// >= 3 tile-times ago -> zero stall) ; BAR ; 16 ds_read + 32 MFMA ; BAR ;
// stage tile t+3 into the buffer just freed. Tail: clamped re-stage of tile 47
// keeps per-wave vmcnt counts uniform. No vmcnt(0) drain anywhere in the loop.
#define STAGE3(buf)                                                           \
    do {                                                                      \
        GLD16(pAl, (buf) + wq1);            GLD16(pAh, (buf) + wq1 + 8192);   \
        GLD16(pHl, (buf) + 16384 + wq1);    GLD16(pHh, (buf) + 24576 + wq1);  \
        GLD16(pGl, (buf) + 32768 + wq1);    GLD16(pGh, (buf) + 40960 + wq1);  \
    } while (0)

__global__ __launch_bounds__(512, 2) void k_gemm(const bf16_t* __restrict__ xq,
                                                 const bf16_t* __restrict__ wq,
                                                 const bf16_t* __restrict__ T,
                                                 const bf16_t* __restrict__ lub,
                                                 float* __restrict__ out) {
    __shared__ __align__(16) char smem[147456];      // 3 x 48 KB circular

    int tid = threadIdx.x, lane = tid & 63, w = tid >> 6;
    int half = w >> 2;                 // 0 = H, 1 = G
    int wr = (w & 3) >> 1, wc = w & 1;

    // XCD-bijective swizzle (grid 1536 % 8 == 0)
    int nwg = gridDim.x;
    int cpx = nwg >> 3;
    int swz = (blockIdx.x & 7) * cpx + (blockIdx.x >> 3);
    int mt = swz & 31, nt = swz >> 5;  // mt fast: neighbors share B tiles
    int m0 = mt * BM, c0 = nt * BN;

    f32x4 acc[4][4];
#pragma unroll
    for (int i = 0; i < 4; ++i)
#pragma unroll
        for (int j = 0; j < 4; ++j) acc[i][j] = (f32x4){0.f, 0.f, 0.f, 0.f};

    // hoisted per-thread staging pointers (both-sides swizzle folded into source;
    // row+64 == row mod 8 -> same XOR column for lo/hi chunk). Each thread loads
    // rows (tid>>3) and (tid>>3)+64 of each 128x64 tile.
    const int srow = tid >> 3;
    const int sgc = ((tid & 7) ^ (srow & 7)) * 8;
    const int wq1 = tid * 16;                        // linear LDS dest, bytes
    const bf16_t* pAl = xq + (size_t)(m0 + srow) * DIN + sgc;
    const bf16_t* pAh = pAl + (size_t)64 * DIN;
    const bf16_t* pHl = wq + (size_t)(c0 + srow) * DIN + sgc;
    const bf16_t* pHh = pHl + (size_t)64 * DIN;
    const bf16_t* pGl = pHl + (size_t)HALF * DIN;
    const bf16_t* pGh = pGl + (size_t)64 * DIN;

    // ---- prologue: stage tiles 0,1,2 into bufs 0,1,2 ----
#pragma unroll
    for (int p = 0; p < 3; ++p) {
        char* buf = smem + p * 49152;
        STAGE3(buf);
        pAl += BK; pAh += BK; pHl += BK; pHh += BK; pGl += BK; pGh += BK;
    }
    // pointers now at tile 3

    int cb = 0;
    for (int t = 0; t < NT; ++t) {
        WAITV(12);            // tile t landed; tiles t+1,t+2 (12 loads) in flight
        BAR();
        SCHED0();

        const char* sAb = smem + cb * 49152;
        const char* sBb = sAb + 16384 + (half << 14);

#pragma unroll
        for (int ks = 0; ks < 2; ++ks) {
            int c16 = ks * 4 + (lane >> 4);
            bf16x8 a[4], b[4];
#pragma unroll
            for (int i = 0; i < 4; ++i) {
                int ra = wr * 64 + i * 16 + (lane & 15);
                int rb = wc * 64 + i * 16 + (lane & 15);
                a[i] = *reinterpret_cast<const bf16x8*>(sAb + ra * 128 + ((c16 ^ (ra & 7)) << 4));
                b[i] = *reinterpret_cast<const bf16x8*>(sBb + rb * 128 + ((c16 ^ (rb & 7)) << 4));
            }
#pragma unroll
            for (int m = 0; m < 4; ++m)
#pragma unroll
                for (int n = 0; n < 4; ++n)
                    acc[m][n] = __builtin_amdgcn_mfma_f32_16x16x32_bf16(a[m], b[n], acc[m][n], 0, 0, 0);
        }

        BAR();                // all waves' reads of buf[cb] done -> safe to overwrite
        SCHED0();

        {
            char* buf = smem + cb * 49152;
            STAGE3(buf);      // tile min(t+3, NT-1)
        }
        const int adv = (t + 4 < NT) ? BK : 0;       // clamp tail at tile NT-1
        pAl += adv; pAh += adv; pHl += adv; pHh += adv; pGl += adv; pGh += adv;

        cb = (cb == 2) ? 0 : cb + 1;
    }

    // ---- LoRA correction: one K=32 MFMA per fragment (RANK == 32) ----
    {
        bf16x8 tf[4];
#pragma unroll
        for (int m = 0; m < 4; ++m)
            tf[m] = *reinterpret_cast<const bf16x8*>(
                T + (size_t)(m0 + wr * 64 + m * 16 + (lane & 15)) * 32 + (lane >> 4) * 8);
#pragma unroll
        for (int n = 0; n < 4; ++n) {
            bf16x8 lu = *reinterpret_cast<const bf16x8*>(
                lub + (size_t)(c0 + half * HALF + wc * 64 + n * 16 + (lane & 15)) * 32 + (lane >> 4) * 8);
#pragma unroll
            for (int m = 0; m < 4; ++m)
                acc[m][n] = __builtin_amdgcn_mfma_f32_16x16x32_bf16(tf[m], lu, acc[m][n], 0, 0, 0);
        }
    }

    // ---- GEGLU epilogue via f32 LDS exchange (reuse smem; drain DMA first) ----
    WAITV(0);                 // redundant tail stages may still be in flight
    __syncthreads();
    float* exch = (float*)smem;         // [128][128] f32, col XOR-swizzled
    if (half) {
#pragma unroll
        for (int m = 0; m < 4; ++m)
#pragma unroll
            for (int n = 0; n < 4; ++n) {
                int col = wc * 64 + n * 16 + (lane & 15);
#pragma unroll
                for (int r = 0; r < 4; ++r) {
                    int row = wr * 64 + m * 16 + (lane >> 4) * 4 + r;
                    float g = acc[m][n][r];
                    float gl = 0.5f * g * (1.0f + erff(g * 0.70710678118654752f));
                    exch[row * 128 + (col ^ (((row >> 2) & 3) << 4))] = gl;
                }
            }
    }
    __syncthreads();
    if (!half) {
#pragma unroll
        for (int m = 0; m < 4; ++m)
#pragma unroll
            for (int n = 0; n < 4; ++n) {
                int col = wc * 64 + n * 16 + (lane & 15);
#pragma unroll
                for (int r = 0; r < 4; ++r) {
                    int row = wr * 64 + m * 16 + (lane >> 4) * 4 + r;
                    float gl = exch[row * 128 + (col ^ (((row >> 2) & 3) << 4))];
                    out[(size_t)(m0 + row) * HALF + c0 + col] = acc[m][n][r] * gl;
                }
            }
    }
}

extern "C" void kernel_launch(void* const* d_in, const int* in_sizes, int n_in,
                              void* d_out, int out_size, void* d_ws, size_t ws_size,
                              hipStream_t stream) {
    const float* x  = (const float*)d_in[0];   // [1,4096,3072]
    const float* wr = (const float*)d_in[1];   // [24576,3072]
    const float* ld = (const float*)d_in[2];   // [32,3072]
    const float* lu = (const float*)d_in[3];   // [24576,32]
    float* out = (float*)d_out;                // [4096,12288] f32

    bf16_t* xq  = (bf16_t*)d_ws;
    bf16_t* wq  = xq + (size_t)MTOK * DIN;
    bf16_t* T   = wq + (size_t)NOUT * DIN;
    bf16_t* lub = T  + (size_t)MTOK * 32;

    k_prep<<<NB_PREP, 256, 0, stream>>>(x, wr, ld, lu, xq, wq, T, lub);
    k_gemm<<<(MTOK / BM) * (HALF / BN), 512, 0, stream>>>(xq, wq, T, lub, out);
}

// Round 12
// 946.557 us; speedup vs baseline: 4.0477x; 1.0090x over previous
//
#include <hip/hip_runtime.h>
#include <hip/hip_bf16.h>
#include <math.h>

typedef __bf16 bf16_t;
typedef __bf16 bf16x4 __attribute__((ext_vector_type(4)));
typedef __bf16 bf16x8 __attribute__((ext_vector_type(8)));
typedef float  f32x4  __attribute__((ext_vector_type(4)));

#define DIN   3072
#define NOUT  24576
#define HALF  12288
#define MTOK  4096
#define BM    128
#define BN    128
#define BK    32
#define NT    96          // DIN / BK

// fused-prepass block ranges (small kernels first: overlap under quant_w's body)
#define NB_LORA  (MTOK / 8)                       // 512
#define NB_QX    (MTOK)                           // 4096
#define NB_CVT   (NOUT * 32 / 4 / 256)            // 768
#define NB_QW    (NOUT * (DIN / 4) / 256)         // 73728
#define B0       (NB_LORA)
#define B1       (B0 + NB_QX)
#define B2       (B1 + NB_CVT)
#define NB_PREP  (B2 + NB_QW)

#define GLD16(gp, lp) \
    __builtin_amdgcn_global_load_lds((const __attribute__((address_space(1))) void*)(gp), \
                                     (__attribute__((address_space(3))) void*)(lp), 16, 0, 0)

#define BAR()    __builtin_amdgcn_s_barrier()
#define WAITV(N) asm volatile("s_waitcnt vmcnt(" #N ")" ::: "memory")
#define SCHED0() __builtin_amdgcn_sched_barrier(0)

// ---------------- fused prepass: lora_t | quant_x | cvt_lu | quant_w --------------
__global__ __launch_bounds__(256) void k_prep(const float* __restrict__ x,
                                              const float* __restrict__ w,
                                              const float* __restrict__ ld,
                                              const float* __restrict__ lu,
                                              bf16_t* __restrict__ xq,
                                              bf16_t* __restrict__ wq,
                                              bf16_t* __restrict__ T,
                                              bf16_t* __restrict__ lub) {
    const int bid = blockIdx.x;
    const int t = threadIdx.x;

    if (bid < B0) {
        // ---- T = x @ lora_down^T (full-precision x), 8 tokens x 32 ranks ----
        int r = t & 31;
        int m = bid * 8 + (t >> 5);
        const float4* xr = reinterpret_cast<const float4*>(x + (size_t)m * DIN);
        const float4* lr = reinterpret_cast<const float4*>(ld + (size_t)r * DIN);
        float acc = 0.f;
#pragma unroll 4
        for (int i = 0; i < DIN / 4; ++i) {
            float4 a = xr[i], b = lr[i];
            acc += a.x * b.x + a.y * b.y + a.z * b.z + a.w * b.w;
        }
        T[(size_t)m * 32 + r] = (bf16_t)acc;
    } else if (bid < B1) {
        // ---- per-token activation int4 fake-quant -> bf16 ----
        int m = bid - B0;
        const float4* row = reinterpret_cast<const float4*>(x + (size_t)m * DIN);
        float4 v[3];
        float vm = 0.f;
#pragma unroll
        for (int i = 0; i < 3; ++i) {
            v[i] = row[t + i * 256];
            vm = fmaxf(vm, fmaxf(fmaxf(fabsf(v[i].x), fabsf(v[i].y)),
                                 fmaxf(fabsf(v[i].z), fabsf(v[i].w))));
        }
#pragma unroll
        for (int d = 1; d < 64; d <<= 1) vm = fmaxf(vm, __shfl_xor(vm, d));
        __shared__ float sm[4];
        if ((t & 63) == 0) sm[t >> 6] = vm;
        __syncthreads();
        vm = fmaxf(fmaxf(sm[0], sm[1]), fmaxf(sm[2], sm[3]));
        float s = fmaxf(vm * (1.f / 7.f), 1e-8f);
        float inv = 1.f / s;
        bf16x4* orow = reinterpret_cast<bf16x4*>(xq + (size_t)m * DIN);
#pragma unroll
        for (int i = 0; i < 3; ++i) {
            bf16x4 o;
            o[0] = (bf16_t)(fminf(fmaxf(rintf(v[i].x * inv), -8.f), 7.f) * s);
            o[1] = (bf16_t)(fminf(fmaxf(rintf(v[i].y * inv), -8.f), 7.f) * s);
            o[2] = (bf16_t)(fminf(fmaxf(rintf(v[i].z * inv), -8.f), 7.f) * s);
            o[3] = (bf16_t)(fminf(fmaxf(rintf(v[i].w * inv), -8.f), 7.f) * s);
            orow[t + i * 256] = o;
        }
    } else if (bid < B2) {
        // ---- cast lora_up f32 -> bf16 ----
        size_t idx = (size_t)(bid - B1) * 256 + t;
        float4 v = reinterpret_cast<const float4*>(lu)[idx];
        bf16x4 o;
        o[0] = (bf16_t)v.x; o[1] = (bf16_t)v.y; o[2] = (bf16_t)v.z; o[3] = (bf16_t)v.w;
        reinterpret_cast<bf16x4*>(lub)[idx] = o;
    } else {
        // ---- per-(row, group-of-64) weight int4 fake-quant -> bf16 ----
        size_t idx = (size_t)(bid - B2) * 256 + t;   // float4 index
        float4 v = reinterpret_cast<const float4*>(w)[idx];
        float vm = fmaxf(fmaxf(fabsf(v.x), fabsf(v.y)), fmaxf(fabsf(v.z), fabsf(v.w)));
        vm = fmaxf(vm, __shfl_xor(vm, 1));
        vm = fmaxf(vm, __shfl_xor(vm, 2));
        vm = fmaxf(vm, __shfl_xor(vm, 4));
        vm = fmaxf(vm, __shfl_xor(vm, 8));
        float s = fmaxf(vm * (1.f / 7.f), 1e-8f);
        float inv = 1.f / s;
        bf16x4 o;
        o[0] = (bf16_t)(fminf(fmaxf(rintf(v.x * inv), -8.f), 7.f) * s);
        o[1] = (bf16_t)(fminf(fmaxf(rintf(v.y * inv), -8.f), 7.f) * s);
        o[2] = (bf16_t)(fminf(fmaxf(rintf(v.z * inv), -8.f), 7.f) * s);
        o[3] = (bf16_t)(fminf(fmaxf(rintf(v.w * inv), -8.f), 7.f) * s);
        reinterpret_cast<bf16x4*>(wq)[idx] = o;
    }
}

// ---------------- K4: BK=32 double-buffered fused GEMM, 2 blocks/CU ---------------
// 512 thr = 8 waves. Waves 0-3: H tile (2x2 of 64x64); waves 4-7: G tile.
// LDS: dbuf 2 x 24KB {A 8K | BH 8K | BG 8K} = 48KB -> 2 blocks/CU preserved.
// Per K-tile: STAGE(t+1 -> buf^1) first; reads(buf)+16 MFMA (compiler lgkm);
// WAITV(0) covered by the tile's compute (DMA issued a full tile earlier);
// ONE BAR serves WAR (buf^1 reads done) + visibility (all waves' DMA waited).
//
// LDS chunk mapping (conflict-uniform, bijective; write<->read verified):
//   write: chunk i = tid: line=i>>3, s=i&7, r=2*line+(s>>2), c=((s&3)-line)&3
//          LDS bytes [i*16,+16) <- global row r, elems c*8..c*8+7
//   read (row R, 16B-col C=lane>>4): addr = (R>>1)*128 + ((((C+(R>>1))&3)|((R&1)<<2))<<4)
// 64 lanes -> 8 lanes per 16B slot uniform = b128 minimum = zero counted conflicts.
__global__ __launch_bounds__(512, 2) void k_gemm(const bf16_t* __restrict__ xq,
                                                 const bf16_t* __restrict__ wq,
                                                 const bf16_t* __restrict__ T,
                                                 const bf16_t* __restrict__ lub,
                                                 float* __restrict__ out) {
    __shared__ __align__(16) char smem[49152];       // 2 x 24KB dbuf; epilogue exch

    int tid = threadIdx.x, lane = tid & 63, w = tid >> 6;
    int half = w >> 2;                 // 0 = H, 1 = G
    int wr = (w & 3) >> 1, wc = w & 1;
    const int l15 = lane & 15, C4 = lane >> 4;

    // XCD-bijective swizzle (grid 3072 % 8 == 0)
    int nwg = gridDim.x;
    int cpx = nwg >> 3;
    int swz = (blockIdx.x & 7) * cpx + (blockIdx.x >> 3);
    int mt = swz & 31, nt = swz >> 5;  // mt fast: neighbors share B tiles
    int m0 = mt * BM, c0 = nt * BN;

    f32x4 acc[4][4];
#pragma unroll
    for (int i = 0; i < 4; ++i)
#pragma unroll
        for (int j = 0; j < 4; ++j) acc[i][j] = (f32x4){0.f, 0.f, 0.f, 0.f};

    // staging source pointers (inverse chunk mapping, hoisted; +BK elems per tile)
    const int sline = tid >> 3, ss = tid & 7;
    const int srow = 2 * sline + (ss >> 2);
    const int scol = (((ss & 3) - sline) & 3) * 8;
    const int ldst = tid * 16;                        // linear LDS dest bytes
    const bf16_t* pA = xq + (size_t)(m0 + srow) * DIN + scol;
    const bf16_t* pH = wq + (size_t)(c0 + srow) * DIN + scol;
    const bf16_t* pG = pH + (size_t)HALF * DIN;

    // read byte-offsets within an 8KB region (hoisted, 4 A + 4 B)
    int offA[4], offB[4];
#pragma unroll
    for (int i = 0; i < 4; ++i) {
        int R = wr * 64 + i * 16 + l15;
        offA[i] = (R >> 1) * 128 + (((((C4 + (R >> 1)) & 3)) | ((R & 1) << 2)) << 4);
        int Rb = wc * 64 + i * 16 + l15;
        offB[i] = (Rb >> 1) * 128 + (((((C4 + (Rb >> 1)) & 3)) | ((Rb & 1) << 2)) << 4);
    }

#define STAGE32(nb)                                                           \
    do {                                                                      \
        GLD16(pA, (nb) + ldst);                                               \
        GLD16(pH, (nb) + 8192 + ldst);                                        \
        GLD16(pG, (nb) + 16384 + ldst);                                       \
    } while (0)

    // ---- prologue: stage tile 0 into buf0 ----
    STAGE32((char*)smem);
    pA += BK; pH += BK; pG += BK;
    WAITV(0);
    BAR();
    SCHED0();

    for (int t = 0; t < NT; ++t) {
        const char* base = (const char*)smem + (t & 1) * 24576;
        char* nb = (char*)smem + ((t + 1) & 1) * 24576;

        STAGE32(nb);          // tile t+1 (last iter: redundant re-stage of NT-1)

        const char* sB = base + 8192 + (half << 13);
        bf16x8 a[4], b[4];
#pragma unroll
        for (int i = 0; i < 4; ++i) {
            a[i] = *reinterpret_cast<const bf16x8*>(base + offA[i]);
            b[i] = *reinterpret_cast<const bf16x8*>(sB + offB[i]);
        }
#pragma unroll
        for (int m = 0; m < 4; ++m)
#pragma unroll
            for (int n = 0; n < 4; ++n)
                acc[m][n] = __builtin_amdgcn_mfma_f32_16x16x32_bf16(a[m], b[n], acc[m][n], 0, 0, 0);

        WAITV(0);             // covered: t+1's DMA flew during this tile's compute
        BAR();                // WAR (buf^1 reads done) + cross-wave visibility
        SCHED0();

        const int adv = (t + 2 < NT) ? BK : 0;
        pA += adv; pH += adv; pG += adv;
    }

    // ---- LoRA correction: one K=32 MFMA per fragment (RANK == 32) ----
    {
        bf16x8 tf[4];
#pragma unroll
        for (int m = 0; m < 4; ++m)
            tf[m] = *reinterpret_cast<const bf16x8*>(
                T + (size_t)(m0 + wr * 64 + m * 16 + l15) * 32 + C4 * 8);
#pragma unroll
        for (int n = 0; n < 4; ++n) {
            bf16x8 lu = *reinterpret_cast<const bf16x8*>(
                lub + (size_t)(c0 + half * HALF + wc * 64 + n * 16 + l15) * 32 + C4 * 8);
#pragma unroll
            for (int m = 0; m < 4; ++m)
                acc[m][n] = __builtin_amdgcn_mfma_f32_16x16x32_bf16(tf[m], lu, acc[m][n], 0, 0, 0);
        }
    }

    // ---- GEGLU epilogue via bf16 LDS exchange [128][132] (pad kills conflicts) ----
    __syncthreads();                    // staging fully drained by last loop BAR
    bf16_t* exch = (bf16_t*)smem;
    if (half) {
#pragma unroll
        for (int m = 0; m < 4; ++m)
#pragma unroll
            for (int n = 0; n < 4; ++n) {
                int col = wc * 64 + n * 16 + l15;
#pragma unroll
                for (int r = 0; r < 4; ++r) {
                    int row = wr * 64 + m * 16 + C4 * 4 + r;
                    float g = acc[m][n][r];
                    float gl = 0.5f * g * (1.0f + erff(g * 0.70710678118654752f));
                    exch[row * 132 + col] = (bf16_t)gl;
                }
            }
    }
    __syncthreads();
    if (!half) {
#pragma unroll
        for (int m = 0; m < 4; ++m)
#pragma unroll
            for (int n = 0; n < 4; ++n) {
                int col = wc * 64 + n * 16 + l15;
#pragma unroll
                for (int r = 0; r < 4; ++r) {
                    int row = wr * 64 + m * 16 + C4 * 4 + r;
                    float gl = (float)exch[row * 132 + col];
                    out[(size_t)(m0 + row) * HALF + c0 + col] = acc[m][n][r] * gl;
                }
            }
    }
#undef STAGE32
}

extern "C" void kernel_launch(void* const* d_in, const int* in_sizes, int n_in,
                              void* d_out, int out_size, void* d_ws, size_t ws_size,
                              hipStream_t stream) {
    const float* x  = (const float*)d_in[0];   // [1,4096,3072]
    const float* wr = (const float*)d_in[1];   // [24576,3072]
    const float* ld = (const float*)d_in[2];   // [32,3072]
    const float* lu = (const float*)d_in[3];   // [24576,32]
    float* out = (float*)d_out;                // [4096,12288] f32

    bf16_t* xq  = (bf16_t*)d_ws;
    bf16_t* wq  = xq + (size_t)MTOK * DIN;
    bf16_t* T   = wq + (size_t)NOUT * DIN;
    bf16_t* lub = T  + (size_t)MTOK * 32;

    k_prep<<<NB_PREP, 256, 0, stream>>>(x, wr, ld, lu, xq, wq, T, lub);
    k_gemm<<<(MTOK / BM) * (HALF / BN), 512, 0, stream>>>(xq, wq, T, lub, out);
}

// Round 14
// 762.899 us; speedup vs baseline: 5.0222x; 1.2407x over previous
//
#include <hip/hip_runtime.h>
#include <hip/hip_bf16.h>
#include <math.h>

typedef __bf16 bf16_t;
typedef __bf16 bf16x4 __attribute__((ext_vector_type(4)));
typedef __bf16 bf16x8 __attribute__((ext_vector_type(8)));
typedef float  f32x4  __attribute__((ext_vector_type(4)));

#define DIN   3072
#define NOUT  24576
#define HALF  12288
#define MTOK  4096
#define BM    128
#define BN    128
#define BK    64

// fused-prepass block ranges (small kernels first: overlap under quant_w's body)
#define NB_LORA  (MTOK / 8)                       // 512
#define NB_QX    (MTOK)                           // 4096
#define NB_CVT   (NOUT * 32 / 4 / 256)            // 768
#define NB_QW    (NOUT * (DIN / 4) / 256)         // 73728
#define B0       (NB_LORA)
#define B1       (B0 + NB_QX)
#define B2       (B1 + NB_CVT)
#define NB_PREP  (B2 + NB_QW)

#define GLD16(gp, lp) \
    __builtin_amdgcn_global_load_lds((const __attribute__((address_space(1))) void*)(gp), \
                                     (__attribute__((address_space(3))) void*)(lp), 16, 0, 0)

// ---------------- fused prepass: lora_t | quant_x | cvt_lu | quant_w --------------
__global__ __launch_bounds__(256) void k_prep(const float* __restrict__ x,
                                              const float* __restrict__ w,
                                              const float* __restrict__ ld,
                                              const float* __restrict__ lu,
                                              bf16_t* __restrict__ xq,
                                              bf16_t* __restrict__ wq,
                                              bf16_t* __restrict__ T,
                                              bf16_t* __restrict__ lub) {
    const int bid = blockIdx.x;
    const int t = threadIdx.x;

    if (bid < B0) {
        // ---- T = x @ lora_down^T (full-precision x), 8 tokens x 32 ranks ----
        int r = t & 31;
        int m = bid * 8 + (t >> 5);
        const float4* xr = reinterpret_cast<const float4*>(x + (size_t)m * DIN);
        const float4* lr = reinterpret_cast<const float4*>(ld + (size_t)r * DIN);
        float acc = 0.f;
#pragma unroll 4
        for (int i = 0; i < DIN / 4; ++i) {
            float4 a = xr[i], b = lr[i];
            acc += a.x * b.x + a.y * b.y + a.z * b.z + a.w * b.w;
        }
        T[(size_t)m * 32 + r] = (bf16_t)acc;
    } else if (bid < B1) {
        // ---- per-token activation int4 fake-quant -> bf16 ----
        int m = bid - B0;
        const float4* row = reinterpret_cast<const float4*>(x + (size_t)m * DIN);
        float4 v[3];
        float vm = 0.f;
#pragma unroll
        for (int i = 0; i < 3; ++i) {
            v[i] = row[t + i * 256];
            vm = fmaxf(vm, fmaxf(fmaxf(fabsf(v[i].x), fabsf(v[i].y)),
                                 fmaxf(fabsf(v[i].z), fabsf(v[i].w))));
        }
#pragma unroll
        for (int d = 1; d < 64; d <<= 1) vm = fmaxf(vm, __shfl_xor(vm, d));
        __shared__ float sm[4];
        if ((t & 63) == 0) sm[t >> 6] = vm;
        __syncthreads();
        vm = fmaxf(fmaxf(sm[0], sm[1]), fmaxf(sm[2], sm[3]));
        float s = fmaxf(vm * (1.f / 7.f), 1e-8f);
        float inv = 1.f / s;
        bf16x4* orow = reinterpret_cast<bf16x4*>(xq + (size_t)m * DIN);
#pragma unroll
        for (int i = 0; i < 3; ++i) {
            bf16x4 o;
            o[0] = (bf16_t)(fminf(fmaxf(rintf(v[i].x * inv), -8.f), 7.f) * s);
            o[1] = (bf16_t)(fminf(fmaxf(rintf(v[i].y * inv), -8.f), 7.f) * s);
            o[2] = (bf16_t)(fminf(fmaxf(rintf(v[i].z * inv), -8.f), 7.f) * s);
            o[3] = (bf16_t)(fminf(fmaxf(rintf(v[i].w * inv), -8.f), 7.f) * s);
            orow[t + i * 256] = o;
        }
    } else if (bid < B2) {
        // ---- cast lora_up f32 -> bf16 ----
        size_t idx = (size_t)(bid - B1) * 256 + t;
        float4 v = reinterpret_cast<const float4*>(lu)[idx];
        bf16x4 o;
        o[0] = (bf16_t)v.x; o[1] = (bf16_t)v.y; o[2] = (bf16_t)v.z; o[3] = (bf16_t)v.w;
        reinterpret_cast<bf16x4*>(lub)[idx] = o;
    } else {
        // ---- per-(row, group-of-64) weight int4 fake-quant -> bf16 ----
        // w is read-once: non-temporal load (ext_vector type: builtin requires it)
        size_t idx = (size_t)(bid - B2) * 256 + t;   // f32x4 index
        f32x4 v = __builtin_nontemporal_load(reinterpret_cast<const f32x4*>(w) + idx);
        float vm = fmaxf(fmaxf(fabsf(v[0]), fabsf(v[1])), fmaxf(fabsf(v[2]), fabsf(v[3])));
        vm = fmaxf(vm, __shfl_xor(vm, 1));
        vm = fmaxf(vm, __shfl_xor(vm, 2));
        vm = fmaxf(vm, __shfl_xor(vm, 4));
        vm = fmaxf(vm, __shfl_xor(vm, 8));
        float s = fmaxf(vm * (1.f / 7.f), 1e-8f);
        float inv = 1.f / s;
        bf16x4 o;
        o[0] = (bf16_t)(fminf(fmaxf(rintf(v[0] * inv), -8.f), 7.f) * s);
        o[1] = (bf16_t)(fminf(fmaxf(rintf(v[1] * inv), -8.f), 7.f) * s);
        o[2] = (bf16_t)(fminf(fmaxf(rintf(v[2] * inv), -8.f), 7.f) * s);
        o[3] = (bf16_t)(fminf(fmaxf(rintf(v[3] * inv), -8.f), 7.f) * s);
        reinterpret_cast<bf16x4*>(wq)[idx] = o;
    }
}

// ---------------- K4: fused GEMM (h + gate tiles) + LoRA + GEGLU ------------------
// EXACT r9 structure (measured best: 721-734 us, 0 conflicts, 46% occupancy),
// + non-temporal output stores: the 197 MB f32 out-stream no longer evicts wq
// from L2/L3 -> staged loads hit cache -> shorter vmcnt(0) drains per K-tile.
__global__ __launch_bounds__(512, 2) void k_gemm(const bf16_t* __restrict__ xq,
                                                 const bf16_t* __restrict__ wq,
                                                 const bf16_t* __restrict__ T,
                                                 const bf16_t* __restrict__ lub,
                                                 float* __restrict__ out) {
    __shared__ __align__(16) char smem[65536];       // staging 48KB; epilogue exch 64KB
    bf16_t* sA = (bf16_t*)smem;                      // [128][64]
    bf16_t* sH = sA + BM * BK;
    bf16_t* sG = sH + BN * BK;

    int tid = threadIdx.x, lane = tid & 63, w = tid >> 6;
    int half = w >> 2;                 // 0 = H, 1 = G
    int wr = (w & 3) >> 1, wc = w & 1;

    // XCD-bijective swizzle (grid 1536 % 8 == 0)
    int nwg = gridDim.x;
    int cpx = nwg >> 3;
    int swz = (blockIdx.x & 7) * cpx + (blockIdx.x >> 3);
    int mt = swz & 31, nt = swz >> 5;  // mt fast: neighbors share B tiles
    int m0 = mt * BM, c0 = nt * BN;

    f32x4 acc[4][4];
#pragma unroll
    for (int i = 0; i < 4; ++i)
#pragma unroll
        for (int j = 0; j < 4; ++j) acc[i][j] = (f32x4){0.f, 0.f, 0.f, 0.f};

    const char* sBb = (const char*)(half ? sG : sH);
    const char* sAb = (const char*)sA;

    for (int k0 = 0; k0 < DIN; k0 += BK) {
        __syncthreads();
        // stage 3 tiles of 128x64 bf16; 1024 16B-chunks each; 512 lanes -> 2 rounds.
#pragma unroll
        for (int r = 0; r < 2; ++r) {
            int chunk = r * 512 + tid;
            int row = chunk >> 3;
            int gc = ((chunk & 7) ^ (row & 7)) * 8;
            int ldsoff = r * 4096 + w * 512;
            GLD16(xq + (size_t)(m0 + row) * DIN + k0 + gc, sA + ldsoff);
            GLD16(wq + (size_t)(c0 + row) * DIN + k0 + gc, sH + ldsoff);
            GLD16(wq + (size_t)(c0 + HALF + row) * DIN + k0 + gc, sG + ldsoff);
        }
        __syncthreads();   // vmcnt(0) drain before barrier

#pragma unroll
        for (int ks = 0; ks < 2; ++ks) {
            int c16 = ks * 4 + (lane >> 4);
            bf16x8 a[4], b[4];
#pragma unroll
            for (int i = 0; i < 4; ++i) {
                int ra = wr * 64 + i * 16 + (lane & 15);
                int rb = wc * 64 + i * 16 + (lane & 15);
                a[i] = *reinterpret_cast<const bf16x8*>(sAb + ra * 128 + ((c16 ^ (ra & 7)) << 4));
                b[i] = *reinterpret_cast<const bf16x8*>(sBb + rb * 128 + ((c16 ^ (rb & 7)) << 4));
            }
#pragma unroll
            for (int m = 0; m < 4; ++m)
#pragma unroll
                for (int n = 0; n < 4; ++n)
                    acc[m][n] = __builtin_amdgcn_mfma_f32_16x16x32_bf16(a[m], b[n], acc[m][n], 0, 0, 0);
        }
    }

    // ---- LoRA correction: one K=32 MFMA per fragment (RANK == 32) ----
    {
        bf16x8 tf[4];
#pragma unroll
        for (int m = 0; m < 4; ++m)
            tf[m] = *reinterpret_cast<const bf16x8*>(
                T + (size_t)(m0 + wr * 64 + m * 16 + (lane & 15)) * 32 + (lane >> 4) * 8);
#pragma unroll
        for (int n = 0; n < 4; ++n) {
            bf16x8 lu = *reinterpret_cast<const bf16x8*>(
                lub + (size_t)(c0 + half * HALF + wc * 64 + n * 16 + (lane & 15)) * 32 + (lane >> 4) * 8);
#pragma unroll
            for (int m = 0; m < 4; ++m)
                acc[m][n] = __builtin_amdgcn_mfma_f32_16x16x32_bf16(tf[m], lu, acc[m][n], 0, 0, 0);
        }
    }

    // ---- GEGLU epilogue via LDS exchange; non-temporal f32 stores ----
    __syncthreads();                    // all LDS staging reads done; reuse smem
    float* exch = (float*)smem;         // [128][128] f32, col XOR-swizzled
    if (half) {
#pragma unroll
        for (int m = 0; m < 4; ++m)
#pragma unroll
            for (int n = 0; n < 4; ++n) {
                int col = wc * 64 + n * 16 + (lane & 15);
#pragma unroll
                for (int r = 0; r < 4; ++r) {
                    int row = wr * 64 + m * 16 + (lane >> 4) * 4 + r;
                    float g = acc[m][n][r];
                    float gl = 0.5f * g * (1.0f + erff(g * 0.70710678118654752f));
                    exch[row * 128 + (col ^ (((row >> 2) & 3) << 4))] = gl;
                }
            }
    }
    __syncthreads();
    if (!half) {
#pragma unroll
        for (int m = 0; m < 4; ++m)
#pragma unroll
            for (int n = 0; n < 4; ++n) {
                int col = wc * 64 + n * 16 + (lane & 15);
#pragma unroll
                for (int r = 0; r < 4; ++r) {
                    int row = wr * 64 + m * 16 + (lane >> 4) * 4 + r;
                    float gl = exch[row * 128 + (col ^ (((row >> 2) & 3) << 4))];
                    __builtin_nontemporal_store(acc[m][n][r] * gl,
                                                &out[(size_t)(m0 + row) * HALF + c0 + col]);
                }
            }
    }
}

extern "C" void kernel_launch(void* const* d_in, const int* in_sizes, int n_in,
                              void* d_out, int out_size, void* d_ws, size_t ws_size,
                              hipStream_t stream) {
    const float* x  = (const float*)d_in[0];   // [1,4096,3072]
    const float* wr = (const float*)d_in[1];   // [24576,3072]
    const float* ld = (const float*)d_in[2];   // [32,3072]
    const float* lu = (const float*)d_in[3];   // [24576,32]
    float* out = (float*)d_out;                // [4096,12288] f32

    bf16_t* xq  = (bf16_t*)d_ws;
    bf16_t* wq  = xq + (size_t)MTOK * DIN;
    bf16_t* T   = wq + (size_t)NOUT * DIN;
    bf16_t* lub = T  + (size_t)MTOK * 32;

    k_prep<<<NB_PREP, 256, 0, stream>>>(x, wr, ld, lu, xq, wq, T, lub);
    k_gemm<<<(MTOK / BM) * (HALF / BN), 512, 0, stream>>>(xq, wq, T, lub, out);
}

// Round 15
// 755.268 us; speedup vs baseline: 5.0729x; 1.0101x over previous
//
#include <hip/hip_runtime.h>
#include <hip/hip_bf16.h>
#include <math.h>

typedef __bf16 bf16_t;
typedef __bf16 bf16x4 __attribute__((ext_vector_type(4)));
typedef __bf16 bf16x8 __attribute__((ext_vector_type(8)));
typedef float  f32x4  __attribute__((ext_vector_type(4)));

#define DIN   3072
#define NOUT  24576
#define HALF  12288
#define MTOK  4096
#define BM    128
#define BN    128
#define BK    64

// fused-prepass block ranges (small kernels first: overlap under quant_w's body)
#define NB_LORA  (MTOK / 8)                       // 512
#define NB_QX    (MTOK)                           // 4096
#define NB_CVT   (NOUT * 32 / 4 / 256)            // 768
#define NB_QW    (NOUT * (DIN / 4) / 256)         // 73728
#define B0       (NB_LORA)
#define B1       (B0 + NB_QX)
#define B2       (B1 + NB_CVT)
#define NB_PREP  (B2 + NB_QW)

#define GLD16(gp, lp) \
    __builtin_amdgcn_global_load_lds((const __attribute__((address_space(1))) void*)(gp), \
                                     (__attribute__((address_space(3))) void*)(lp), 16, 0, 0)

// ---------------- fused prepass: lora_t | quant_x | cvt_lu | quant_w --------------
__global__ __launch_bounds__(256) void k_prep(const float* __restrict__ x,
                                              const float* __restrict__ w,
                                              const float* __restrict__ ld,
                                              const float* __restrict__ lu,
                                              bf16_t* __restrict__ xq,
                                              bf16_t* __restrict__ wq,
                                              bf16_t* __restrict__ T,
                                              bf16_t* __restrict__ lub) {
    const int bid = blockIdx.x;
    const int t = threadIdx.x;

    if (bid < B0) {
        // ---- T = x @ lora_down^T (full-precision x), 8 tokens x 32 ranks ----
        int r = t & 31;
        int m = bid * 8 + (t >> 5);
        const float4* xr = reinterpret_cast<const float4*>(x + (size_t)m * DIN);
        const float4* lr = reinterpret_cast<const float4*>(ld + (size_t)r * DIN);
        float acc = 0.f;
#pragma unroll 4
        for (int i = 0; i < DIN / 4; ++i) {
            float4 a = xr[i], b = lr[i];
            acc += a.x * b.x + a.y * b.y + a.z * b.z + a.w * b.w;
        }
        T[(size_t)m * 32 + r] = (bf16_t)acc;
    } else if (bid < B1) {
        // ---- per-token activation int4 fake-quant -> bf16 ----
        int m = bid - B0;
        const float4* row = reinterpret_cast<const float4*>(x + (size_t)m * DIN);
        float4 v[3];
        float vm = 0.f;
#pragma unroll
        for (int i = 0; i < 3; ++i) {
            v[i] = row[t + i * 256];
            vm = fmaxf(vm, fmaxf(fmaxf(fabsf(v[i].x), fabsf(v[i].y)),
                                 fmaxf(fabsf(v[i].z), fabsf(v[i].w))));
        }
#pragma unroll
        for (int d = 1; d < 64; d <<= 1) vm = fmaxf(vm, __shfl_xor(vm, d));
        __shared__ float sm[4];
        if ((t & 63) == 0) sm[t >> 6] = vm;
        __syncthreads();
        vm = fmaxf(fmaxf(sm[0], sm[1]), fmaxf(sm[2], sm[3]));
        float s = fmaxf(vm * (1.f / 7.f), 1e-8f);
        float inv = 1.f / s;
        bf16x4* orow = reinterpret_cast<bf16x4*>(xq + (size_t)m * DIN);
#pragma unroll
        for (int i = 0; i < 3; ++i) {
            bf16x4 o;
            o[0] = (bf16_t)(fminf(fmaxf(rintf(v[i].x * inv), -8.f), 7.f) * s);
            o[1] = (bf16_t)(fminf(fmaxf(rintf(v[i].y * inv), -8.f), 7.f) * s);
            o[2] = (bf16_t)(fminf(fmaxf(rintf(v[i].z * inv), -8.f), 7.f) * s);
            o[3] = (bf16_t)(fminf(fmaxf(rintf(v[i].w * inv), -8.f), 7.f) * s);
            orow[t + i * 256] = o;
        }
    } else if (bid < B2) {
        // ---- cast lora_up f32 -> bf16 ----
        size_t idx = (size_t)(bid - B1) * 256 + t;
        float4 v = reinterpret_cast<const float4*>(lu)[idx];
        bf16x4 o;
        o[0] = (bf16_t)v.x; o[1] = (bf16_t)v.y; o[2] = (bf16_t)v.z; o[3] = (bf16_t)v.w;
        reinterpret_cast<bf16x4*>(lub)[idx] = o;
    } else {
        // ---- per-(row, group-of-64) weight int4 fake-quant -> bf16 ----
        // w is read-once: non-temporal load (ext_vector type: builtin requires it)
        size_t idx = (size_t)(bid - B2) * 256 + t;   // f32x4 index
        f32x4 v = __builtin_nontemporal_load(reinterpret_cast<const f32x4*>(w) + idx);
        float vm = fmaxf(fmaxf(fabsf(v[0]), fabsf(v[1])), fmaxf(fabsf(v[2]), fabsf(v[3])));
        vm = fmaxf(vm, __shfl_xor(vm, 1));
        vm = fmaxf(vm, __shfl_xor(vm, 2));
        vm = fmaxf(vm, __shfl_xor(vm, 4));
        vm = fmaxf(vm, __shfl_xor(vm, 8));
        float s = fmaxf(vm * (1.f / 7.f), 1e-8f);
        float inv = 1.f / s;
        bf16x4 o;
        o[0] = (bf16_t)(fminf(fmaxf(rintf(v[0] * inv), -8.f), 7.f) * s);
        o[1] = (bf16_t)(fminf(fmaxf(rintf(v[1] * inv), -8.f), 7.f) * s);
        o[2] = (bf16_t)(fminf(fmaxf(rintf(v[2] * inv), -8.f), 7.f) * s);
        o[3] = (bf16_t)(fminf(fmaxf(rintf(v[3] * inv), -8.f), 7.f) * s);
        reinterpret_cast<bf16x4*>(wq)[idx] = o;
    }
}

// ---------------- K4: fused GEMM (h + gate tiles) + LoRA + GEGLU ------------------
// r14 structure (612 us, MfmaUtil ~50%) + coalesced epilogue:
// G waves write gelu(g) to exch; H waves read gl and overwrite the SAME slot with
// h*gl in-place (each slot touched by exactly one lane -> race-free); then all
// 8 waves stream exch out linearly as f32x4 nt-stores (full-line HBM writes).
__global__ __launch_bounds__(512, 2) void k_gemm(const bf16_t* __restrict__ xq,
                                                 const bf16_t* __restrict__ wq,
                                                 const bf16_t* __restrict__ T,
                                                 const bf16_t* __restrict__ lub,
                                                 float* __restrict__ out) {
    __shared__ __align__(16) char smem[65536];       // staging 48KB; epilogue exch 64KB
    bf16_t* sA = (bf16_t*)smem;                      // [128][64]
    bf16_t* sH = sA + BM * BK;
    bf16_t* sG = sH + BN * BK;

    int tid = threadIdx.x, lane = tid & 63, w = tid >> 6;
    int half = w >> 2;                 // 0 = H, 1 = G
    int wr = (w & 3) >> 1, wc = w & 1;

    // XCD-bijective swizzle (grid 1536 % 8 == 0)
    int nwg = gridDim.x;
    int cpx = nwg >> 3;
    int swz = (blockIdx.x & 7) * cpx + (blockIdx.x >> 3);
    int mt = swz & 31, nt = swz >> 5;  // mt fast: neighbors share B tiles
    int m0 = mt * BM, c0 = nt * BN;

    f32x4 acc[4][4];
#pragma unroll
    for (int i = 0; i < 4; ++i)
#pragma unroll
        for (int j = 0; j < 4; ++j) acc[i][j] = (f32x4){0.f, 0.f, 0.f, 0.f};

    const char* sBb = (const char*)(half ? sG : sH);
    const char* sAb = (const char*)sA;

    for (int k0 = 0; k0 < DIN; k0 += BK) {
        __syncthreads();
        // stage 3 tiles of 128x64 bf16; 1024 16B-chunks each; 512 lanes -> 2 rounds.
#pragma unroll
        for (int r = 0; r < 2; ++r) {
            int chunk = r * 512 + tid;
            int row = chunk >> 3;
            int gc = ((chunk & 7) ^ (row & 7)) * 8;
            int ldsoff = r * 4096 + w * 512;
            GLD16(xq + (size_t)(m0 + row) * DIN + k0 + gc, sA + ldsoff);
            GLD16(wq + (size_t)(c0 + row) * DIN + k0 + gc, sH + ldsoff);
            GLD16(wq + (size_t)(c0 + HALF + row) * DIN + k0 + gc, sG + ldsoff);
        }
        __syncthreads();   // vmcnt(0) drain before barrier

#pragma unroll
        for (int ks = 0; ks < 2; ++ks) {
            int c16 = ks * 4 + (lane >> 4);
            bf16x8 a[4], b[4];
#pragma unroll
            for (int i = 0; i < 4; ++i) {
                int ra = wr * 64 + i * 16 + (lane & 15);
                int rb = wc * 64 + i * 16 + (lane & 15);
                a[i] = *reinterpret_cast<const bf16x8*>(sAb + ra * 128 + ((c16 ^ (ra & 7)) << 4));
                b[i] = *reinterpret_cast<const bf16x8*>(sBb + rb * 128 + ((c16 ^ (rb & 7)) << 4));
            }
#pragma unroll
            for (int m = 0; m < 4; ++m)
#pragma unroll
                for (int n = 0; n < 4; ++n)
                    acc[m][n] = __builtin_amdgcn_mfma_f32_16x16x32_bf16(a[m], b[n], acc[m][n], 0, 0, 0);
        }
    }

    // ---- LoRA correction: one K=32 MFMA per fragment (RANK == 32) ----
    {
        bf16x8 tf[4];
#pragma unroll
        for (int m = 0; m < 4; ++m)
            tf[m] = *reinterpret_cast<const bf16x8*>(
                T + (size_t)(m0 + wr * 64 + m * 16 + (lane & 15)) * 32 + (lane >> 4) * 8);
#pragma unroll
        for (int n = 0; n < 4; ++n) {
            bf16x8 lu = *reinterpret_cast<const bf16x8*>(
                lub + (size_t)(c0 + half * HALF + wc * 64 + n * 16 + (lane & 15)) * 32 + (lane >> 4) * 8);
#pragma unroll
            for (int m = 0; m < 4; ++m)
                acc[m][n] = __builtin_amdgcn_mfma_f32_16x16x32_bf16(tf[m], lu, acc[m][n], 0, 0, 0);
        }
    }

    // ---- GEGLU epilogue: exch gl -> in-place product -> coalesced nt stores ----
    __syncthreads();                    // all LDS staging reads done; reuse smem
    float* exch = (float*)smem;         // [128][128] f32, col XOR-swizzled
    if (half) {
#pragma unroll
        for (int m = 0; m < 4; ++m)
#pragma unroll
            for (int n = 0; n < 4; ++n) {
                int col = wc * 64 + n * 16 + (lane & 15);
#pragma unroll
                for (int r = 0; r < 4; ++r) {
                    int row = wr * 64 + m * 16 + (lane >> 4) * 4 + r;
                    float g = acc[m][n][r];
                    float gl = 0.5f * g * (1.0f + erff(g * 0.70710678118654752f));
                    exch[row * 128 + (col ^ (((row >> 2) & 3) << 4))] = gl;
                }
            }
    }
    __syncthreads();
    if (!half) {
        // in-place: each slot read+written by the same lane only
#pragma unroll
        for (int m = 0; m < 4; ++m)
#pragma unroll
            for (int n = 0; n < 4; ++n) {
                int col = wc * 64 + n * 16 + (lane & 15);
#pragma unroll
                for (int r = 0; r < 4; ++r) {
                    int row = wr * 64 + m * 16 + (lane >> 4) * 4 + r;
                    int sidx = row * 128 + (col ^ (((row >> 2) & 3) << 4));
                    exch[sidx] = acc[m][n][r] * exch[sidx];
                }
            }
    }
    __syncthreads();
    // all 8 waves: stream 64 KB out, 16B/lane coalesced, full-line nt writes
#pragma unroll
    for (int i = 0; i < 8; ++i) {
        int idx = i * 512 + tid;        // f32x4 chunk id, 4096 total
        int row = idx >> 5;             // 32 chunks per 128-col row
        int c4 = idx & 31;
        f32x4 v = *reinterpret_cast<const f32x4*>(
            exch + row * 128 + ((c4 ^ (((row >> 2) & 3) << 2)) << 2));
        __builtin_nontemporal_store(v, reinterpret_cast<f32x4*>(
            out + (size_t)(m0 + row) * HALF + c0 + c4 * 4));
    }
}

extern "C" void kernel_launch(void* const* d_in, const int* in_sizes, int n_in,
                              void* d_out, int out_size, void* d_ws, size_t ws_size,
                              hipStream_t stream) {
    const float* x  = (const float*)d_in[0];   // [1,4096,3072]
    const float* wr = (const float*)d_in[1];   // [24576,3072]
    const float* ld = (const float*)d_in[2];   // [32,3072]
    const float* lu = (const float*)d_in[3];   // [24576,32]
    float* out = (float*)d_out;                // [4096,12288] f32

    bf16_t* xq  = (bf16_t*)d_ws;
    bf16_t* wq  = xq + (size_t)MTOK * DIN;
    bf16_t* T   = wq + (size_t)NOUT * DIN;
    bf16_t* lub = T  + (size_t)MTOK * 32;

    k_prep<<<NB_PREP, 256, 0, stream>>>(x, wr, ld, lu, xq, wq, T, lub);
    k_gemm<<<(MTOK / BM) * (HALF / BN), 512, 0, stream>>>(xq, wq, T, lub, out);
}